// Round 6
// baseline (59.735 us; speedup 1.0000x reference)
//
#include <hip/hip_runtime.h>
#include <stdint.h>

// LearnedTripleConnect: B=8,N=8192,S=8,D=64. out[b,n] = mean_s( gelu([xi|xj|xk]W1+b1) ) W2 + b2
// Round 6: chunk-major LDS layout -> every GEMM1 ds_read_b128 is a contiguous 1KB wave access
// (zero bank conflicts, imm-offset addressing). Same staging instr count / LDS size as round 5.

#define NT   4            // 64-token tiles per block
#define NBLK 2048         // 2048*4*64 = 524288 tokens

typedef short  short8 __attribute__((ext_vector_type(8)));
typedef float  f32x4  __attribute__((ext_vector_type(4)));
typedef float  f32x16 __attribute__((ext_vector_type(16)));

__device__ __forceinline__ unsigned short f2bf(float f){
  union { float f; unsigned u; } a; a.f = f;
  unsigned u = a.u;
  u += 0x7fffu + ((u >> 16) & 1u);   // RNE
  return (unsigned short)(u >> 16);
}
__device__ __forceinline__ float fast_gelu(float x){
  // x * sigmoid(1.5957691*(x + 0.044715 x^3)) via exp2; |err vs exact gelu| ~3e-4
  float x2 = x * x;
  float t  = __builtin_fmaf(x2, -0.1029437f, -2.3022083f);
  float p  = __builtin_amdgcn_exp2f(x * t);
  return x * __builtin_amdgcn_rcpf(1.0f + p);
}

// ---------------- fused prep ----------------
__global__ void prep_kernel(const float* __restrict__ x, const float* __restrict__ W1,
                            const float* __restrict__ W2, short* __restrict__ xb,
                            short* __restrict__ w1f, short* __restrict__ w2f){
  int bid = blockIdx.x;
  if (bid < 2048){
    long i = (long)bid * 256 + threadIdx.x;   // 0..524287, 8 elems each
    const float4* p = (const float4*)(x + i * 8);
    float4 a = p[0], b = p[1];
    short8 v;
    v[0]=(short)f2bf(a.x); v[1]=(short)f2bf(a.y); v[2]=(short)f2bf(a.z); v[3]=(short)f2bf(a.w);
    v[4]=(short)f2bf(b.x); v[5]=(short)f2bf(b.y); v[6]=(short)f2bf(b.z); v[7]=(short)f2bf(b.w);
    *(short8*)(xb + i * 8) = v;
  } else if (threadIdx.x < 64){
    int f = bid - 2048, lane = threadIdx.x;
    short8 v;
    if (f < 48){
      int cb = f / 12, t = f % 12;
      #pragma unroll
      for (int j = 0; j < 8; j++)
        v[j] = (short)f2bf(W1[(t*16 + 8*(lane>>5) + j)*128 + cb*32 + (lane&31)]);
      *(short8*)(w1f + ((long)(f*64 + lane))*8) = v;
    } else {
      int g = f - 48; int w = g >> 2, q = g & 3;
      #pragma unroll
      for (int j = 0; j < 8; j++)
        v[j] = (short)f2bf(W2[(q*32 + 8*(lane>>4) + j)*64 + w*16 + (lane&15)]);
      *(short8*)(w2f + ((long)(g*64 + lane))*8) = v;
    }
  }
}

// ---------------- main kernel ----------------
// Per-tile LDS (17 KB), chunk-major:
//   own  [0,1024)B:  group g at g*512:  slot = chunk*4 + r4   (4 rows/group, dedup over s)
//   j [1024,9216)B:  group g at g*4096: slot = chunk*32 + r32
//   k [9216,17408)B: same + 8192
// GEMM1 k-step t reads 64 consecutive slots -> contiguous 1KB, conflict-free.
__global__ __launch_bounds__(512, 4) void ltc_main(
    const short* __restrict__ xb,  const short* __restrict__ w1f,
    const short* __restrict__ w2f, const int* __restrict__ jidx,
    const int* __restrict__ kidx,  const float* __restrict__ b1,
    const float* __restrict__ b2,  float* __restrict__ out)
{
  __shared__ short Ab[2][8704];     // 2 x 17 KB
  __shared__ short HB[2][16 * 136]; // hbar ping-pong: 8 valid rows x 128 h, stride 136

  const int tid  = threadIdx.x;
  const int w    = tid >> 6, lane = tid & 63;
  const int cb   = w & 3,  rb  = w >> 2;
  const int l31  = lane & 31, hi = lane >> 5;
  const int l15  = lane & 15, q4 = lane >> 4;

  // resident weight fragments
  short8 w1v[12];
  #pragma unroll
  for (int t = 0; t < 12; t++)
    w1v[t] = *(const short8*)(w1f + ((long)((cb * 12 + t) * 64 + lane)) * 8);
  short8 w2v[4];
  #pragma unroll
  for (int q = 0; q < 4; q++)
    w2v[q] = *(const short8*)(w2f + ((long)((cb * 4 + q) * 64 + lane)) * 8);

  float b1v = b1[cb * 32 + l31];
  float b2v = b2[cb * 16 + l15];

  // zero HB rows 8-15 of both buffers (GEMM2 A-frag garbage rows; results discarded)
  for (int i = tid; i < 8 * 136; i += 512){ HB[0][8*136 + i] = 0; HB[1][8*136 + i] = 0; }

  const int bid   = blockIdx.x;
  const int batch = bid & 7;
  const int T0    = batch * 1024 + (bid >> 3) * NT;   // batch-affine XCD swizzle
  const long tb0  = (long)T0 * 64;
  const int bbase = batch << 13;                      // batch row base (b*8192)

  // staging roles: wave w stages token-group sg = w>>2, chunk-pair scp = w&3 for j and k
  const int sg   = w >> 2;
  const int scp  = w & 3;
  const int t_st = sg * 32 + l31;                     // tile-local token whose idx this lane loads
  // own staging (wave 0): lane l -> (g=l>>5, c=(l>>2)&7, r4=l&3)
  const int o_g  = lane >> 5, o_c = (lane >> 2) & 7, o_r4 = lane & 3;

  // GEMM1 read base byte offsets (+= t*128 / t*1024 per k-step)
  const int r4l = l31 >> 3;
  const int oO  = rb * 512  + hi * 64  + r4l * 16;
  const int oJ  = 1024 + rb * 4096 + hi * 512 + l31 * 16;
  const int oK  = oJ + 8192;

  auto stage = [&](int buf, long tb, int jn, int kn){
    const short* gj = xb + (long)(bbase + jn) * 64 + (scp * 2 + hi) * 8;
    __builtin_amdgcn_global_load_lds(
        (const __attribute__((address_space(1))) unsigned int*)gj,
        (__attribute__((address_space(3))) unsigned int*)(&Ab[buf][512 + sg * 2048 + scp * 512]),
        16, 0, 0);
    const short* gk = xb + (long)(bbase + kn) * 64 + (scp * 2 + hi) * 8;
    __builtin_amdgcn_global_load_lds(
        (const __attribute__((address_space(1))) unsigned int*)gk,
        (__attribute__((address_space(3))) unsigned int*)(&Ab[buf][4608 + sg * 2048 + scp * 512]),
        16, 0, 0);
    if (w == 0){
      const short* go = xb + (long)((int)(tb >> 3) + o_g * 4 + o_r4) * 64 + o_c * 8;
      __builtin_amdgcn_global_load_lds(
          (const __attribute__((address_space(1))) unsigned int*)go,
          (__attribute__((address_space(3))) unsigned int*)(&Ab[buf][0]), 16, 0, 0);
    }
  };

  auto gemm2_store = [&](int buf, int ttp){
    f32x4 acc2 = {0.f, 0.f, 0.f, 0.f};
    #pragma unroll
    for (int q = 0; q < 4; q++){
      short8 hbf = *(const short8*)&HB[buf][l15 * 136 + q * 32 + q4 * 8];
      acc2 = __builtin_amdgcn_mfma_f32_16x16x32_bf16(hbf, w2v[q], acc2, 0, 0, 0);
    }
    if (lane < 32){                       // rows 0-7 valid
      long G = ((long)(T0 + ttp)) * 8;
      #pragma unroll
      for (int r = 0; r < 4; r++)
        out[(G + 4 * q4 + r) * 64 + cb * 16 + l15] = acc2[r] + b2v;
    }
  };

  // prologue
  int jn0 = jidx[tb0 + t_st], kn0 = kidx[tb0 + t_st];
  stage(0, tb0, jn0, kn0);
  int jnS = 0, knS = 0;
  if (NT > 1){ jnS = jidx[tb0 + 64 + t_st]; knS = kidx[tb0 + 64 + t_st]; }

  for (int tt = 0; tt < NT; ++tt){
    const int cur = tt & 1;
    asm volatile("s_waitcnt vmcnt(0) lgkmcnt(0)\n\ts_barrier" ::: "memory");  // Ab[cur]+HB[cur^1] ready
    if (tt + 1 < NT) stage(cur ^ 1, tb0 + (long)(tt + 1) * 64, jnS, knS);
    if (tt + 2 < NT){
      jnS = jidx[tb0 + (long)(tt + 2) * 64 + t_st];
      knS = kidx[tb0 + (long)(tt + 2) * 64 + t_st];
    }

    // deferred GEMM2 of previous tile (HB published by this tile's top barrier)
    if (tt > 0 && w < 4) gemm2_store(cur ^ 1, tt - 1);

    // GEMM1: C[32 tok][32 h], C-init = b1
    const char* Abase = (const char*)&Ab[cur][0];
    f32x16 acc;
    #pragma unroll
    for (int r = 0; r < 16; r++) acc[r] = b1v;
    #pragma unroll
    for (int t = 0; t < 12; t++){
      int off;
      if (t < 4)       off = oO + t * 128;
      else if (t < 8)  off = oJ + (t - 4) * 1024;
      else             off = oK + (t - 8) * 1024;
      short8 af = *(const short8*)(Abase + off);
      acc = __builtin_amdgcn_mfma_f32_32x32x16_bf16(af, w1v[t], acc, 0, 0, 0);
    }

    // GELU + s-reduce: token row=(reg&3)+8*(reg>>2)+4*hi -> group o=reg>>2, s=(reg&3)+4*hi
    #pragma unroll
    for (int o = 0; o < 4; o++){
      float s0 = fast_gelu(acc[4*o+0]);
      s0 += fast_gelu(acc[4*o+1]);
      s0 += fast_gelu(acc[4*o+2]);
      s0 += fast_gelu(acc[4*o+3]);
      float other = __shfl_xor(s0, 32);
      float hbv = (s0 + other) * 0.125f;
      if (hi == 0)
        HB[cur][(rb * 4 + o) * 136 + cb * 32 + l31] = (short)f2bf(hbv);
    }
  }

  // epilogue: last tile's GEMM2
  asm volatile("s_waitcnt lgkmcnt(0)\n\ts_barrier" ::: "memory");
  if (w < 4) gemm2_store((NT - 1) & 1, NT - 1);
}

// ---------------- fallback (ws too small): correct, slow ----------------
__global__ void ltc_naive(const float* __restrict__ x, const int* __restrict__ jidx,
                          const int* __restrict__ kidx, const float* __restrict__ W1,
                          const float* __restrict__ b1, const float* __restrict__ W2,
                          const float* __restrict__ b2, float* __restrict__ out)
{
  int gidx = blockIdx.x;            // b*8192+n
  int b = gidx >> 13;
  __shared__ float trip[8][192];
  __shared__ float hb[128];
  int t = threadIdx.x;              // 128
  for (int i = t; i < 8 * 192; i += 128){
    int s = i / 192, c = i - s * 192;
    int v = c >> 6, cc = c & 63;
    int src;
    if (v == 0)      src = gidx & 8191;
    else if (v == 1) src = jidx[gidx * 8 + s];
    else             src = kidx[gidx * 8 + s];
    trip[s][c] = x[((long)(b << 13) + src) * 64 + cc];
  }
  __syncthreads();
  float z[8];
  #pragma unroll
  for (int s = 0; s < 8; s++) z[s] = b1[t];
  for (int k = 0; k < 192; k++){
    float wv = W1[k * 128 + t];
    #pragma unroll
    for (int s = 0; s < 8; s++) z[s] = fmaf(trip[s][k], wv, z[s]);
  }
  float acc = 0.f;
  #pragma unroll
  for (int s = 0; s < 8; s++) acc += fast_gelu(z[s]);
  hb[t] = acc * 0.125f;
  __syncthreads();
  if (t < 64){
    float o = b2[t];
    for (int h = 0; h < 128; h++) o = fmaf(hb[h], W2[h * 64 + t], o);
    out[(long)gidx * 64 + t] = o;
  }
}

extern "C" void kernel_launch(void* const* d_in, const int* in_sizes, int n_in,
                              void* d_out, int out_size, void* d_ws, size_t ws_size,
                              hipStream_t stream) {
  const float* x   = (const float*)d_in[0];
  const int*   jix = (const int*)  d_in[1];
  const int*   kix = (const int*)  d_in[2];
  const float* W1  = (const float*)d_in[3];
  const float* b1  = (const float*)d_in[4];
  const float* W2  = (const float*)d_in[5];
  const float* b2  = (const float*)d_in[6];
  float* out = (float*)d_out;

  const size_t xb_elems  = (size_t)8 * 8192 * 64;        // 4,194,304 bf16
  const size_t w1f_elems = 48 * 64 * 8;
  const size_t w2f_elems = 16 * 64 * 8;
  const size_t need = (xb_elems + w1f_elems + w2f_elems) * sizeof(short);

  if (ws_size >= need){
    short* xb  = (short*)d_ws;
    short* w1f = xb + xb_elems;
    short* w2f = w1f + w1f_elems;
    prep_kernel<<<2112, 256, 0, stream>>>(x, W1, W2, xb, w1f, w2f);
    ltc_main<<<NBLK, 512, 0, stream>>>(xb, w1f, w2f, jix, kix, b1, b2, out);
  } else {
    ltc_naive<<<8 * 8192, 128, 0, stream>>>(x, jix, kix, W1, b1, W2, b2, out);
  }
}

// Round 7
// 56.460 us; speedup vs baseline: 1.0580x; 1.0580x over previous
//
#include <hip/hip_runtime.h>
#include <stdint.h>

// LearnedTripleConnect: B=8,N=8192,S=8,D=64. out[b,n] = mean_s( gelu([xi|xj|xk]W1+b1) ) W2 + b2
// Round 7: 256-thread blocks (4 waves, 32-token tiles) -> 4 independent barrier domains/CU
// instead of 2. Same chunk-major conflict-free LDS, 1 barrier/tile, deferred GEMM2.

#define NT   8            // 32-token tiles per block
#define NBLK 2048         // 2048*8*32 = 524288 tokens

typedef short  short8 __attribute__((ext_vector_type(8)));
typedef float  f32x4  __attribute__((ext_vector_type(4)));
typedef float  f32x16 __attribute__((ext_vector_type(16)));

__device__ __forceinline__ unsigned short f2bf(float f){
  union { float f; unsigned u; } a; a.f = f;
  unsigned u = a.u;
  u += 0x7fffu + ((u >> 16) & 1u);   // RNE
  return (unsigned short)(u >> 16);
}
__device__ __forceinline__ float fast_gelu(float x){
  // x * sigmoid(1.5957691*(x + 0.044715 x^3)) via exp2; |err vs exact gelu| ~3e-4
  float x2 = x * x;
  float t  = __builtin_fmaf(x2, -0.1029437f, -2.3022083f);
  float p  = __builtin_amdgcn_exp2f(x * t);
  return x * __builtin_amdgcn_rcpf(1.0f + p);
}

// ---------------- fused prep ----------------
__global__ void prep_kernel(const float* __restrict__ x, const float* __restrict__ W1,
                            const float* __restrict__ W2, short* __restrict__ xb,
                            short* __restrict__ w1f, short* __restrict__ w2f){
  int bid = blockIdx.x;
  if (bid < 2048){
    long i = (long)bid * 256 + threadIdx.x;   // 0..524287, 8 elems each
    const float4* p = (const float4*)(x + i * 8);
    float4 a = p[0], b = p[1];
    short8 v;
    v[0]=(short)f2bf(a.x); v[1]=(short)f2bf(a.y); v[2]=(short)f2bf(a.z); v[3]=(short)f2bf(a.w);
    v[4]=(short)f2bf(b.x); v[5]=(short)f2bf(b.y); v[6]=(short)f2bf(b.z); v[7]=(short)f2bf(b.w);
    *(short8*)(xb + i * 8) = v;
  } else if (threadIdx.x < 64){
    int f = bid - 2048, lane = threadIdx.x;
    short8 v;
    if (f < 48){
      int cb = f / 12, t = f % 12;
      #pragma unroll
      for (int j = 0; j < 8; j++)
        v[j] = (short)f2bf(W1[(t*16 + 8*(lane>>5) + j)*128 + cb*32 + (lane&31)]);
      *(short8*)(w1f + ((long)(f*64 + lane))*8) = v;
    } else {
      int g = f - 48; int w = g >> 2, q = g & 3;
      #pragma unroll
      for (int j = 0; j < 8; j++)
        v[j] = (short)f2bf(W2[(q*32 + 8*(lane>>4) + j)*64 + w*16 + (lane&15)]);
      *(short8*)(w2f + ((long)(g*64 + lane))*8) = v;
    }
  }
}

// ---------------- main kernel ----------------
// Per-tile LDS (9216 B), chunk-major:
//   own [slots 0..63]:   slot l written from row (l>>3)&3, chunk (l&7)^((l>>3)&3)  (2x dup)
//   j   [slots 64..319]: wave w instr -> slot (2w+hi)*32 + l31  (chunk-major [c][row])
//   k   [slots 320..575]
// GEMM1 j/k k-step reads = contiguous 1KB, conflict-free; own reads spread via XOR.
__global__ __launch_bounds__(256, 4) void ltc_main(
    const short* __restrict__ xb,  const short* __restrict__ w1f,
    const short* __restrict__ w2f, const int* __restrict__ jidx,
    const int* __restrict__ kidx,  const float* __restrict__ b1,
    const float* __restrict__ b2,  float* __restrict__ out)
{
  __shared__ short Ab[2][4608];     // 2 x 9 KB (576 slots x 8 shorts)
  __shared__ short HB[2][4 * 136];  // hbar ping-pong: 4 rows x 128 h, stride 136

  const int tid  = threadIdx.x;
  const int w    = tid >> 6, lane = tid & 63;   // w = cb = GEMM2 col-tile
  const int l31  = lane & 31, hi = lane >> 5;
  const int l15  = lane & 15, q4 = lane >> 4;

  // resident weight fragments
  short8 w1v[12];
  #pragma unroll
  for (int t = 0; t < 12; t++)
    w1v[t] = *(const short8*)(w1f + ((long)((w * 12 + t) * 64 + lane)) * 8);
  short8 w2v[4];
  #pragma unroll
  for (int q = 0; q < 4; q++)
    w2v[q] = *(const short8*)(w2f + ((long)((w * 4 + q) * 64 + lane)) * 8);

  float b1v = b1[w * 32 + l31];
  float b2v = b2[w * 16 + l15];

  const int bid   = blockIdx.x;
  const int batch = bid & 7;
  const int tile0 = batch * 2048 + (bid >> 3) * NT;   // 32-token tiles, batch-affine XCD swizzle
  const long tb0  = (long)tile0 * 32;
  const int bbase = batch << 13;                      // batch row base (b*8192)

  // own staging source (wave 0): lane l -> row (l>>3)&3, chunk (l&7)^((l>>3)&3)
  const int o_r = (lane >> 3) & 3;
  const int o_c = (lane & 7) ^ o_r;

  // GEMM1 read base byte offsets
  const int rown = l31 >> 3;                 // own row group (n-local)
  const int oOb  = rown * 128;
  const int oJ   = 1024 + hi * 512 + l31 * 16;
  const int oK   = oJ + 4096;

  auto stage = [&](int buf, long tb, int jn, int kn){
    const short* gj = xb + (long)(bbase + jn) * 64 + (2 * w + hi) * 8;
    __builtin_amdgcn_global_load_lds(
        (const __attribute__((address_space(1))) unsigned int*)gj,
        (__attribute__((address_space(3))) unsigned int*)(&Ab[buf][512 + w * 512]), 16, 0, 0);
    const short* gk = xb + (long)(bbase + kn) * 64 + (2 * w + hi) * 8;
    __builtin_amdgcn_global_load_lds(
        (const __attribute__((address_space(1))) unsigned int*)gk,
        (__attribute__((address_space(3))) unsigned int*)(&Ab[buf][2560 + w * 512]), 16, 0, 0);
    if (w == 0){
      const short* go = xb + (long)((int)(tb >> 3) + o_r) * 64 + o_c * 8;
      __builtin_amdgcn_global_load_lds(
          (const __attribute__((address_space(1))) unsigned int*)go,
          (__attribute__((address_space(3))) unsigned int*)(&Ab[buf][0]), 16, 0, 0);
    }
  };

  auto gemm2_store = [&](int buf, int ttp){
    f32x4 acc2 = {0.f, 0.f, 0.f, 0.f};
    #pragma unroll
    for (int q = 0; q < 4; q++){
      // A-frag: hbar[n = l15&3][k = 32q + 8*q4 + j]
      short8 hbf = *(const short8*)((const char*)&HB[buf][0] + (l15 & 3) * 272 + q * 64 + q4 * 16);
      acc2 = __builtin_amdgcn_mfma_f32_16x16x32_bf16(hbf, w2v[q], acc2, 0, 0, 0);
    }
    if (lane < 16){                       // C rows 0-3 = the 4 valid n
      long Gn = ((long)(tile0 + ttp)) * 4;
      #pragma unroll
      for (int r = 0; r < 4; r++)
        out[(Gn + r) * 64 + w * 16 + l15] = acc2[r] + b2v;
    }
  };

  // prologue
  int jn0 = jidx[tb0 + l31], kn0 = kidx[tb0 + l31];
  stage(0, tb0, jn0, kn0);
  int jnS = 0, knS = 0;
  if (NT > 1){ jnS = jidx[tb0 + 32 + l31]; knS = kidx[tb0 + 32 + l31]; }

  for (int tt = 0; tt < NT; ++tt){
    const int cur = tt & 1;
    asm volatile("s_waitcnt vmcnt(0) lgkmcnt(0)\n\ts_barrier" ::: "memory");  // Ab[cur]+HB[cur^1] ready
    if (tt + 1 < NT) stage(cur ^ 1, tb0 + (long)(tt + 1) * 32, jnS, knS);
    if (tt + 2 < NT){
      jnS = jidx[tb0 + (long)(tt + 2) * 32 + l31];
      knS = kidx[tb0 + (long)(tt + 2) * 32 + l31];
    }

    // deferred GEMM2 of previous tile (HB[cur^1] published before this tile's barrier)
    if (tt > 0) gemm2_store(cur ^ 1, tt - 1);

    // GEMM1: C[32 tok][32 h], C-init = b1
    const char* Abase = (const char*)&Ab[cur][0];
    f32x16 acc;
    #pragma unroll
    for (int r = 0; r < 16; r++) acc[r] = b1v;
    #pragma unroll
    for (int t = 0; t < 12; t++){
      int off;
      if (t < 4)       off = oOb + (((2*t + hi) ^ rown) << 4);
      else if (t < 8)  off = oJ + (t - 4) * 1024;
      else             off = oK + (t - 8) * 1024;
      short8 af = *(const short8*)(Abase + off);
      acc = __builtin_amdgcn_mfma_f32_32x32x16_bf16(af, w1v[t], acc, 0, 0, 0);
    }

    // GELU + s-reduce: token row=(reg&3)+8*(reg>>2)+4*hi -> n-group o=reg>>2, s=(reg&3)+4*hi
    #pragma unroll
    for (int o = 0; o < 4; o++){
      float s0 = fast_gelu(acc[4*o+0]);
      s0 += fast_gelu(acc[4*o+1]);
      s0 += fast_gelu(acc[4*o+2]);
      s0 += fast_gelu(acc[4*o+3]);
      float other = __shfl_xor(s0, 32);
      float hbv = (s0 + other) * 0.125f;
      if (hi == 0)
        HB[cur][o * 136 + w * 32 + l31] = (short)f2bf(hbv);
    }
  }

  // epilogue: last tile's GEMM2
  asm volatile("s_waitcnt lgkmcnt(0)\n\ts_barrier" ::: "memory");
  gemm2_store((NT - 1) & 1, NT - 1);
}

// ---------------- fallback (ws too small): correct, slow ----------------
__global__ void ltc_naive(const float* __restrict__ x, const int* __restrict__ jidx,
                          const int* __restrict__ kidx, const float* __restrict__ W1,
                          const float* __restrict__ b1, const float* __restrict__ W2,
                          const float* __restrict__ b2, float* __restrict__ out)
{
  int gidx = blockIdx.x;            // b*8192+n
  int b = gidx >> 13;
  __shared__ float trip[8][192];
  __shared__ float hb[128];
  int t = threadIdx.x;              // 128
  for (int i = t; i < 8 * 192; i += 128){
    int s = i / 192, c = i - s * 192;
    int v = c >> 6, cc = c & 63;
    int src;
    if (v == 0)      src = gidx & 8191;
    else if (v == 1) src = jidx[gidx * 8 + s];
    else             src = kidx[gidx * 8 + s];
    trip[s][c] = x[((long)(b << 13) + src) * 64 + cc];
  }
  __syncthreads();
  float z[8];
  #pragma unroll
  for (int s = 0; s < 8; s++) z[s] = b1[t];
  for (int k = 0; k < 192; k++){
    float wv = W1[k * 128 + t];
    #pragma unroll
    for (int s = 0; s < 8; s++) z[s] = fmaf(trip[s][k], wv, z[s]);
  }
  float acc = 0.f;
  #pragma unroll
  for (int s = 0; s < 8; s++) acc += fast_gelu(z[s]);
  hb[t] = acc * 0.125f;
  __syncthreads();
  if (t < 64){
    float o = b2[t];
    for (int h = 0; h < 128; h++) o = fmaf(hb[h], W2[h * 64 + t], o);
    out[(long)gidx * 64 + t] = o;
  }
}

extern "C" void kernel_launch(void* const* d_in, const int* in_sizes, int n_in,
                              void* d_out, int out_size, void* d_ws, size_t ws_size,
                              hipStream_t stream) {
  const float* x   = (const float*)d_in[0];
  const int*   jix = (const int*)  d_in[1];
  const int*   kix = (const int*)  d_in[2];
  const float* W1  = (const float*)d_in[3];
  const float* b1  = (const float*)d_in[4];
  const float* W2  = (const float*)d_in[5];
  const float* b2  = (const float*)d_in[6];
  float* out = (float*)d_out;

  const size_t xb_elems  = (size_t)8 * 8192 * 64;        // 4,194,304 bf16
  const size_t w1f_elems = 48 * 64 * 8;
  const size_t w2f_elems = 16 * 64 * 8;
  const size_t need = (xb_elems + w1f_elems + w2f_elems) * sizeof(short);

  if (ws_size >= need){
    short* xb  = (short*)d_ws;
    short* w1f = xb + xb_elems;
    short* w2f = w1f + w1f_elems;
    prep_kernel<<<2112, 256, 0, stream>>>(x, W1, W2, xb, w1f, w2f);
    ltc_main<<<NBLK, 256, 0, stream>>>(xb, w1f, w2f, jix, kix, b1, b2, out);
  } else {
    ltc_naive<<<8 * 8192, 128, 0, stream>>>(x, jix, kix, W1, b1, W2, b2, out);
  }
}